// Round 3
// baseline (434.882 us; speedup 1.0000x reference)
//
#include <hip/hip_runtime.h>

// SelfAttnBlock: BN -> QKV 1x1conv -> full 4096x4096 attention (flash-style,
// never materialized) -> 1x1 conv -> residual.  MI355X gfx950.
//
// R3 design notes (R2 + occupancy fix, driven by counters):
//  - R2 counters: k_attn 192us, Occupancy 22% (2 blocks/CU), MfmaUtil 14.7%,
//    VALUBusy 21%, HBM 1.2% -> latency-bound, not BW/compute bound.
//  - Fix: split-K. Each block does 1024 keys (16 t-steps); 2048 blocks
//    -> ~5 resident blocks/CU (VGPR 92, LDS 17KB). Partials combined with
//    f32 HW atomics (unsafeAtomicAdd) into zeroed RES/Z; k_out divides by Z.
//  - BN stats two-phase w/ atomics (k_stats1 512 blocks); a,b computed
//    inline in k_qkv (kills the 64-block k_stats).
//  - Everything else kept from R2: no-max softmax in exp2 domain, QK^T bf16
//    hi/lo (6 MFMAs), P/V single bf16, XOR-swizzled P LDS, single
//    lgkmcnt-only barrier per t-step, K(t+1)/V(t) reg prefetch, setprio.

#define HW 4096
#define CC 64
#define NBATCH 8
#define SPLIT 4
#define TSTEPS 16  // 64-key steps per block
// 0.125 * log2(e): fold attention scale + exp->exp2 conversion into Q
#define QSCALE 0.18033688011112042f

using f32x4 = __attribute__((ext_vector_type(4))) float;
using bf16x8 = __attribute__((ext_vector_type(8))) short;
typedef unsigned short u16;
typedef unsigned int u32;

#if __has_builtin(__builtin_amdgcn_exp2f)
#define EXP2F(v) __builtin_amdgcn_exp2f(v)
#else
#define EXP2F(v) exp2f(v)
#endif

__device__ __forceinline__ u16 f2bf(float v) {  // RNE f32->bf16
  u32 u = __float_as_uint(v);
  return (u16)((u + 0x7fffu + ((u >> 16) & 1u)) >> 16);
}
__device__ __forceinline__ float bf2f(u16 h) {
  return __uint_as_float(((u32)h) << 16);
}

// ---------- kernel 1: BN partial sums (per (n,c) plane) -> atomics into SACC
__global__ __launch_bounds__(256) void k_stats1(const float* __restrict__ x,
                                                float* __restrict__ SACC) {
  const int n = blockIdx.x >> 6;
  const int c = blockIdx.x & 63;
  const int tid = threadIdx.x;
  const float* xp = x + ((size_t)n * CC + c) * HW;
  float s1 = 0.f, s2 = 0.f;
#pragma unroll
  for (int i = tid; i < HW; i += 256) {
    const float v = xp[i];
    s1 += v;
    s2 += v * v;
  }
#pragma unroll
  for (int m = 1; m <= 32; m <<= 1) {
    s1 += __shfl_xor(s1, m);
    s2 += __shfl_xor(s2, m);
  }
  __shared__ float r1[4], r2[4];
  const int w = tid >> 6;
  if ((tid & 63) == 0) { r1[w] = s1; r2[w] = s2; }
  __syncthreads();
  if (tid == 0) {
    unsafeAtomicAdd(SACC + c, r1[0] + r1[1] + r1[2] + r1[3]);
    unsafeAtomicAdd(SACC + CC + c, r2[0] + r2[1] + r2[2] + r2[3]);
  }
}

// ---------- kernel 2: fused BN-apply + Q/K/V 1x1 convs + bf16 hi/lo quantize
// outputs: QH/QL/KH/KL as [n][hw][c] bf16 ; V as [n][c][hw] bf16
__device__ __forceinline__ void mm16(const float* __restrict__ W,
                                     const float* __restrict__ B,
                                     const float* xcol, int o0, float scale,
                                     float* outv) {
#pragma unroll
  for (int oo = 0; oo < 16; ++oo) {
    const int o = o0 + oo;
    float a = B[o];                  // uniform per wave -> SGPR
#pragma unroll
    for (int c = 0; c < CC; ++c) a = fmaf(W[o * CC + c], xcol[c], a);
    outv[oo] = a * scale;
  }
}

__device__ __forceinline__ void split_store16(const float* v16, u16* dh, u16* dl) {
  u32 hi[8], lo[8];
#pragma unroll
  for (int e = 0; e < 8; ++e) {
    const u16 h0 = f2bf(v16[2 * e]), h1 = f2bf(v16[2 * e + 1]);
    const float l0 = v16[2 * e] - bf2f(h0);
    const float l1 = v16[2 * e + 1] - bf2f(h1);
    hi[e] = (u32)h0 | ((u32)h1 << 16);
    lo[e] = (u32)f2bf(l0) | ((u32)f2bf(l1) << 16);
  }
  ((uint4*)dh)[0] = *(const uint4*)&hi[0];
  ((uint4*)dh)[1] = *(const uint4*)&hi[4];
  ((uint4*)dl)[0] = *(const uint4*)&lo[0];
  ((uint4*)dl)[1] = *(const uint4*)&lo[4];
}

__global__ __launch_bounds__(256) void k_qkv(
    const float* __restrict__ x, const float* __restrict__ SACC,
    const float* __restrict__ gamma, const float* __restrict__ beta,
    const float* __restrict__ wq, const float* __restrict__ bq,
    const float* __restrict__ wk, const float* __restrict__ bk,
    const float* __restrict__ wv, const float* __restrict__ bv,
    u16* __restrict__ QH, u16* __restrict__ QL, u16* __restrict__ KH,
    u16* __restrict__ KL, u16* __restrict__ V) {
  const int n = blockIdx.x >> 6;
  const int i0 = (blockIdx.x & 63) << 6;
  __shared__ float xn[CC][64];
  __shared__ float sa[CC], sb[CC];
  const int tid = threadIdx.x;
  if (tid < CC) {  // BN a,b from accumulated stats (biased var, eps=1e-5)
    const float inv = 1.0f / (float)(NBATCH * HW);
    const float mean = SACC[tid] * inv;
    const float var = SACC[CC + tid] * inv - mean * mean;
    const float a = rsqrtf(var + 1e-5f) * gamma[tid];
    sa[tid] = a;
    sb[tid] = beta[tid] - mean * a;
  }
  __syncthreads();
  {
    const int p = tid & 63;
    const int c0 = (tid >> 6) << 4;
    const float* xp = x + (size_t)n * CC * HW + i0 + p;
#pragma unroll
    for (int cc = 0; cc < 16; ++cc) {
      const int c = c0 + cc;
      xn[c][p] = fmaf(xp[(size_t)c * HW], sa[c], sb[c]);
    }
  }
  __syncthreads();
  const int w = tid >> 6;  // wave -> output-channel block (uniform W reads)
  const int p = tid & 63;
  float xcol[CC];
#pragma unroll
  for (int c = 0; c < CC; ++c) xcol[c] = xn[c][p];

  const size_t row = (size_t)n * HW + i0 + p;
  float v16[16];
  mm16(wq, bq, xcol, w * 16, QSCALE, v16);
  split_store16(v16, QH + row * CC + w * 16, QL + row * CC + w * 16);
  mm16(wk, bk, xcol, w * 16, 1.0f, v16);
  split_store16(v16, KH + row * CC + w * 16, KL + row * CC + w * 16);
  mm16(wv, bv, xcol, w * 16, 1.0f, v16);
#pragma unroll
  for (int oo = 0; oo < 16; ++oo)
    V[((size_t)n * CC + w * 16 + oo) * HW + i0 + p] = f2bf(v16[oo]);
}

// ---------- kernel 3: flash attention partial, QB=64 q-rows, 1024 keys/block
__global__ __launch_bounds__(256) void k_attn(
    const u16* __restrict__ QH, const u16* __restrict__ QL,
    const u16* __restrict__ KH, const u16* __restrict__ KL,
    const u16* __restrict__ V, float* __restrict__ RES,
    float* __restrict__ Z) {
  // blockIdx & 7 -> XCD slot: all 256 blocks of batch n colocate on one XCD
  // (per-batch K/V+Q ~3.5MB ~ L2)
  const int n = blockIdx.x & 7;
  const int q0 = ((blockIdx.x >> 3) & 63) << 6;
  const int s = blockIdx.x >> 9;  // key-range split 0..3
  const int tid = threadIdx.x;
  const int w = tid >> 6;
  const int l = tid & 63;
  const int l15 = l & 15;
  const int lg = l >> 4;

  __shared__ alignas(16) u16 P[2][64][64];  // [buf][q][key^((q&7)<<3)]
  __shared__ float ZB[4][64];

  // resident Q B-frags: lane holds Q[q0+qb*16+l15][m*32+lg*8 .. +8]
  bf16x8 qh[4][2], ql[4][2];
  {
    const size_t base = ((size_t)n * HW + q0 + l15) * CC + lg * 8;
#pragma unroll
    for (int qb = 0; qb < 4; ++qb)
#pragma unroll
      for (int m = 0; m < 2; ++m) {
        const size_t off = base + (size_t)qb * 16 * CC + m * 32;
        qh[qb][m] = *(const bf16x8*)(QH + off);
        ql[qb][m] = *(const bf16x8*)(QL + off);
      }
  }

  f32x4 acc[4];
#pragma unroll
  for (int i = 0; i < 4; ++i) acc[i] = (f32x4){0.f, 0.f, 0.f, 0.f};
  float zacc[4] = {0.f, 0.f, 0.f, 0.f};

  const u16* kh_ptr =
      KH + ((size_t)n * HW + s * (TSTEPS * 64) + w * 16 + l15) * CC + lg * 8;
  const u16* kl_ptr =
      KL + ((size_t)n * HW + s * (TSTEPS * 64) + w * 16 + l15) * CC + lg * 8;
  const u16* v_ptr =
      V + ((size_t)n * CC + l15) * HW + s * (TSTEPS * 64) + lg * 8;

  const int swz_w = (l15 & 7) << 3;   // write side: q&7 == l15&7
  const int qr = w * 16 + l15;        // PV read q-row
  const int swz_r = (qr & 7) << 3;

  // preload K(first)
  bf16x8 kh0 = *(const bf16x8*)(kh_ptr);
  bf16x8 kh1 = *(const bf16x8*)(kh_ptr + 32);
  bf16x8 kl0 = *(const bf16x8*)(kl_ptr);
  bf16x8 kl1 = *(const bf16x8*)(kl_ptr + 32);

  for (int t = 0; t < TSTEPS; ++t) {
    const int buf = t & 1;
    // early-issue V(t): consumed after the barrier, hidden under QK MFMAs
    bf16x8 vb[2][4];
#pragma unroll
    for (int m2 = 0; m2 < 2; ++m2)
#pragma unroll
      for (int chb = 0; chb < 4; ++chb)
        vb[m2][chb] =
            *(const bf16x8*)(v_ptr + (size_t)chb * 16 * HW + m2 * 32);
    // prefetch K(t+1); tail reads land in the adjacent ws arrays (mapped,
    // values discarded)
    kh_ptr += 64 * CC;
    kl_ptr += 64 * CC;
    const bf16x8 nkh0 = *(const bf16x8*)(kh_ptr);
    const bf16x8 nkh1 = *(const bf16x8*)(kh_ptr + 32);
    const bf16x8 nkl0 = *(const bf16x8*)(kl_ptr);
    const bf16x8 nkl1 = *(const bf16x8*)(kl_ptr + 32);
#pragma unroll
    for (int qb = 0; qb < 4; ++qb) {
      f32x4 s4 = {0.f, 0.f, 0.f, 0.f};
      // S^T = K*Q with hi/lo error correction (drop Kl*Ql term)
      __builtin_amdgcn_s_setprio(1);
      s4 = __builtin_amdgcn_mfma_f32_16x16x32_bf16(kh0, qh[qb][0], s4, 0, 0, 0);
      s4 = __builtin_amdgcn_mfma_f32_16x16x32_bf16(kh1, qh[qb][1], s4, 0, 0, 0);
      s4 = __builtin_amdgcn_mfma_f32_16x16x32_bf16(kh0, ql[qb][0], s4, 0, 0, 0);
      s4 = __builtin_amdgcn_mfma_f32_16x16x32_bf16(kh1, ql[qb][1], s4, 0, 0, 0);
      s4 = __builtin_amdgcn_mfma_f32_16x16x32_bf16(kl0, qh[qb][0], s4, 0, 0, 0);
      s4 = __builtin_amdgcn_mfma_f32_16x16x32_bf16(kl1, qh[qb][1], s4, 0, 0, 0);
      __builtin_amdgcn_s_setprio(0);
      const float p0 = EXP2F(s4[0]);
      const float p1 = EXP2F(s4[1]);
      const float p2 = EXP2F(s4[2]);
      const float p3 = EXP2F(s4[3]);
      zacc[qb] += (p0 + p1) + (p2 + p3);
      const int qq = qb * 16 + l15;
      const int keyb = (w * 16 + lg * 4) ^ swz_w;
      u32* dst = (u32*)&P[buf][qq][keyb];
      dst[0] = (u32)f2bf(p0) | ((u32)f2bf(p1) << 16);
      dst[1] = (u32)f2bf(p2) | ((u32)f2bf(p3) << 16);
    }
    // barrier WITHOUT vmcnt drain: only LDS (P writes) must be visible;
    // K/V prefetches stay in flight across the barrier.
    asm volatile("s_waitcnt lgkmcnt(0)" ::: "memory");
    __builtin_amdgcn_s_barrier();
#pragma unroll
    for (int m2 = 0; m2 < 2; ++m2) {
      const int kb2 = (m2 * 32 + lg * 8) ^ swz_r;
      const bf16x8 pa = *(const bf16x8*)&P[buf][qr][kb2];
      __builtin_amdgcn_s_setprio(1);
#pragma unroll
      for (int chb = 0; chb < 4; ++chb)
        acc[chb] = __builtin_amdgcn_mfma_f32_16x16x32_bf16(pa, vb[m2][chb],
                                                           acc[chb], 0, 0, 0);
      __builtin_amdgcn_s_setprio(0);
    }
    v_ptr += 64;
    kh0 = nkh0; kh1 = nkh1; kl0 = nkl0; kl1 = nkl1;
  }

  // partial z: reduce key-groups (shfl) then waves (LDS), atomically add
#pragma unroll
  for (int qb = 0; qb < 4; ++qb) {
    zacc[qb] += __shfl_xor(zacc[qb], 16);
    zacc[qb] += __shfl_xor(zacc[qb], 32);
  }
  if (l < 16) {
#pragma unroll
    for (int qb = 0; qb < 4; ++qb) ZB[w][qb * 16 + l] = zacc[qb];
  }
  __syncthreads();
  if (tid < 64)
    unsafeAtomicAdd(Z + (size_t)n * HW + q0 + tid,
                    ZB[0][tid] + ZB[1][tid] + ZB[2][tid] + ZB[3][tid]);
  // partial acc -> RES atomics (unnormalized; k_out divides by Z)
  float* resn = RES + ((size_t)n * HW + q0) * CC;
#pragma unroll
  for (int r = 0; r < 4; ++r) {
    const int qq = w * 16 + lg * 4 + r;
#pragma unroll
    for (int chb = 0; chb < 4; ++chb)
      unsafeAtomicAdd(&resn[(size_t)qq * CC + chb * 16 + l15], acc[chb][r]);
  }
}

// ---------- kernel 4: out = x + wo @ (res/z reshaped) + bo
// res[n] flat [i][ch] == [c2][h2][w2]; conv mixes c2.  Row i = c2*64 + (j>>6).
__global__ __launch_bounds__(256) void k_out(const float* __restrict__ RES,
                                             const float* __restrict__ Z,
                                             const float* __restrict__ x,
                                             const float* __restrict__ wo,
                                             const float* __restrict__ bo,
                                             float* __restrict__ out) {
  const int n = blockIdx.x >> 4;
  const int j = ((blockIdx.x & 15) << 8) + threadIdx.x;  // h2*64+w2
  const float* rn = RES + (size_t)n * HW * CC;
  const float* zb = Z + (size_t)n * HW;
  const int jh = j >> 6;
  float rcol[CC];
#pragma unroll
  for (int c2 = 0; c2 < CC; ++c2)
    rcol[c2] = rn[(size_t)c2 * HW + j] * (1.0f / zb[c2 * 64 + jh]);
  const size_t xb = (size_t)n * CC * HW;
  for (int o = 0; o < CC; ++o) {
    float sacc = bo[o];
#pragma unroll
    for (int c2 = 0; c2 < CC; ++c2)
      sacc = fmaf(wo[o * CC + c2], rcol[c2], sacc);
    out[xb + (size_t)o * HW + j] = x[xb + (size_t)o * HW + j] + sacc;
  }
}

extern "C" void kernel_launch(void* const* d_in, const int* in_sizes, int n_in,
                              void* d_out, int out_size, void* d_ws,
                              size_t ws_size, hipStream_t stream) {
  const float* x = (const float*)d_in[0];
  const float* gamma = (const float*)d_in[1];
  const float* beta = (const float*)d_in[2];
  const float* wq = (const float*)d_in[3];
  const float* bq = (const float*)d_in[4];
  const float* wk = (const float*)d_in[5];
  const float* bk = (const float*)d_in[6];
  const float* wv = (const float*)d_in[7];
  const float* bv = (const float*)d_in[8];
  const float* wo = (const float*)d_in[9];
  const float* bo = (const float*)d_in[10];
  float* out = (float*)d_out;

  char* ws = (char*)d_ws;
  // layout: [SACC 1KB][Z 128KB][RES 8MB][QH|QL|KH|KL|V 5x4MB]  (~28.5MB)
  float* SACC = (float*)ws;
  float* Z = (float*)(ws + 1024);
  float* RES = (float*)(ws + 1024 + (size_t)NBATCH * HW * 4);
  const size_t INIT_BYTES =
      1024 + (size_t)NBATCH * HW * 4 + (size_t)NBATCH * HW * CC * 4;
  const size_t ARR = (size_t)NBATCH * HW * CC;
  u16* QH = (u16*)(ws + INIT_BYTES);
  u16* QL = QH + ARR;
  u16* KH = QL + ARR;
  u16* KL = KH + ARR;
  u16* V = KL + ARR;

  hipMemsetAsync(ws, 0, INIT_BYTES, stream);  // zero SACC, Z, RES
  hipLaunchKernelGGL(k_stats1, dim3(512), dim3(256), 0, stream, x, SACC);
  hipLaunchKernelGGL(k_qkv, dim3(512), dim3(256), 0, stream, x, SACC, gamma,
                     beta, wq, bq, wk, bk, wv, bv, QH, QL, KH, KL, V);
  hipLaunchKernelGGL(k_attn, dim3(2048), dim3(256), 0, stream, QH, QL, KH, KL,
                     V, RES, Z);
  hipLaunchKernelGGL(k_out, dim3(128), dim3(256), 0, stream, RES, Z, x, wo, bo,
                     out);
}